// Round 1
// baseline (799.922 us; speedup 1.0000x reference)
//
#include <hip/hip_runtime.h>
#include <math.h>

typedef unsigned int u32;

// ---------------------------------------------------------------------------
// Problem: Clifford GNN message passing.
//   h: (N,256) f32, edge_index: (2,E) int, edge_type: (E,) int,
//   relation_emb: (R,256) f32, msg_w/upd_w: (4,64,64), msg_b/upd_b: (4,64),
//   gate_w: (1,256), gate_b: (1,)
// Restructured: h_agg = ML(sum_e w_e * (h[src] .* r[rel])) + msg_b * sum_e w_e
// where w_e = gate(rel) * norm(e); then out = UL(h + h_agg) + upd_b (permuted
// store: out[n, c*4+b] = val[b*64+c]).
// ---------------------------------------------------------------------------

// Build transposed 256x256 Clifford kernel matrices Kt[i][j] = K[j][i].
__global__ void build_mats_kernel(const float* __restrict__ msg_w,
                                  const float* __restrict__ upd_w,
                                  float* __restrict__ Ktm,
                                  float* __restrict__ Ktu) {
    const int   s_tab[16] = {0,1,2,3, 1,0,3,2, 2,3,0,1, 3,2,1,0};
    const float g_tab[16] = {1.f,1.f,1.f,-1.f, 1.f,1.f,-1.f,1.f,
                             1.f,1.f,1.f,-1.f, 1.f,1.f,1.f,1.f};
    int idx = blockIdx.x * 256 + threadIdx.x;   // idx = i*256 + j
    int i = idx >> 8, j = idx & 255;
    int ib = i >> 6, ic = i & 63, ob = j >> 6, oc = j & 63;
    int t = ob * 4 + ib;
    int widx = s_tab[t] * 4096 + oc * 64 + ic;  // w[s][oc][ic]
    float sg = g_tab[t];
    Ktm[idx] = sg * msg_w[widx];
    Ktu[idx] = sg * upd_w[widx];
}

// gate[r] = sigmoid( sum_j rel_emb[r, j] * gate_w[(j&63)*4 + (j>>6)] + gate_b )
// (j is blade-major index; gate_w is channel-major per reference reshape)
__global__ void gate_kernel(const float* __restrict__ rel_emb,
                            const float* __restrict__ gate_w,
                            const float* __restrict__ gate_b,
                            float* __restrict__ gate, int R) {
    int wv = threadIdx.x >> 6, lane = threadIdx.x & 63;
    int r = blockIdx.x * 4 + wv;
    if (r >= R) return;
    float4 rv = *(const float4*)(rel_emb + (size_t)r * 256 + lane * 4);
    float s = 0.f;
    float rvv[4] = {rv.x, rv.y, rv.z, rv.w};
#pragma unroll
    for (int c = 0; c < 4; ++c) {
        int j = lane * 4 + c;
        s += rvv[c] * gate_w[(j & 63) * 4 + (j >> 6)];
    }
#pragma unroll
    for (int d = 32; d > 0; d >>= 1) s += __shfl_down(s, d);
    if (lane == 0) gate[r] = 1.0f / (1.0f + expf(-(s + gate_b[0])));
}

__global__ void degree_kernel(const int* __restrict__ ei, int E,
                              u32* __restrict__ deg_src, u32* __restrict__ deg_dst) {
    int e = blockIdx.x * 256 + threadIdx.x;
    if (e >= E) return;
    atomicAdd(&deg_src[ei[e]], 1u);
    atomicAdd(&deg_dst[ei[E + e]], 1u);
}

// Single-block exclusive scan of deg_dst -> offs and cursor (copy).
__global__ void scan_kernel(const u32* __restrict__ deg, u32* __restrict__ offs,
                            u32* __restrict__ cursor, int N) {
    __shared__ u32 wtot[16];
    __shared__ u32 wpre[17];
    __shared__ u32 running;
    int t = threadIdx.x, lane = t & 63, wv = t >> 6;
    if (t == 0) running = 0u;
    __syncthreads();
    for (int base = 0; base < N; base += 4096) {
        int i0 = base + t * 4;
        u32 v[4]; u32 s = 0;
#pragma unroll
        for (int c = 0; c < 4; ++c) { v[c] = (i0 + c < N) ? deg[i0 + c] : 0u; s += v[c]; }
        u32 sc = s;
#pragma unroll
        for (int d = 1; d < 64; d <<= 1) { u32 o = __shfl_up(sc, d); if (lane >= d) sc += o; }
        if (lane == 63) wtot[wv] = sc;
        __syncthreads();
        if (t < 16) {
            u32 x = wtot[t], xs = x;
#pragma unroll
            for (int d = 1; d < 16; d <<= 1) { u32 o = __shfl_up(xs, d); if (t >= d) xs += o; }
            wpre[t] = xs - x;
            if (t == 15) wpre[16] = xs;   // chunk total
        }
        __syncthreads();
        u32 excl = running + wpre[wv] + (sc - s);
#pragma unroll
        for (int c = 0; c < 4; ++c) {
            if (i0 + c < N) { offs[i0 + c] = excl; cursor[i0 + c] = excl; }
            excl += v[c];
        }
        __syncthreads();
        if (t == 0) running += wpre[16];
        __syncthreads();
    }
}

__global__ void fill_kernel(const int* __restrict__ ei, int E,
                            u32* __restrict__ cursor, u32* __restrict__ edge_ids) {
    int e = blockIdx.x * 256 + threadIdx.x;
    if (e >= E) return;
    int dst = ei[E + e];
    u32 pos = atomicAdd(&cursor[dst], 1u);
    edge_ids[pos] = (u32)e;
}

// One wave per node: agg[n] = sum_{e in bucket} w_e * h[src] .* r[rel];
// writes agg row into d_out and w-sum into wsum_arr.
__global__ void agg_kernel(const float* __restrict__ h,
                           const float* __restrict__ rel_emb,
                           const int* __restrict__ ei, const int* __restrict__ et,
                           const u32* __restrict__ deg_src,
                           const u32* __restrict__ deg_dst,
                           const u32* __restrict__ offs,
                           const u32* __restrict__ edge_ids,
                           const float* __restrict__ gate,
                           float* __restrict__ out, float* __restrict__ wsum_arr,
                           int E, int N) {
    int wv = threadIdx.x >> 6, lane = threadIdx.x & 63;
    int n = blockIdx.x * 4 + wv;
    if (n >= N) return;
    u32 dd = deg_dst[n];
    u32 off = offs[n];
    float ddf = (float)dd;
    float4 acc = make_float4(0.f, 0.f, 0.f, 0.f);
    float wsum = 0.f;
    for (u32 i = 0; i < dd; ++i) {
        u32 eid = edge_ids[off + i];
        int src = ei[eid];
        int rel = et[eid];
        float ds = (float)deg_src[src];
        float w = gate[rel] / sqrtf(fmaxf(ds * ddf, 1.0f));
        float4 hv = *(const float4*)(h + (size_t)src * 256 + lane * 4);
        float4 rv = *(const float4*)(rel_emb + (size_t)rel * 256 + lane * 4);
        acc.x += w * hv.x * rv.x;
        acc.y += w * hv.y * rv.y;
        acc.z += w * hv.z * rv.z;
        acc.w += w * hv.w * rv.w;
        wsum += w;
    }
    *(float4*)(out + (size_t)n * 256 + lane * 4) = acc;
    if (lane == 0) wsum_arr[n] = wsum;
}

// In-place tiled GEMM on d_out rows: out_row = Kt^T @ x_row (+extras).
// PHASE 1: t = h + ML(agg) + msg_b*wsum     (x = agg rows in d_out)
// PHASE 2: y = UL(t) + upd_b, permuted store out[n, (j&63)*4 + (j>>6)]
template <int PHASE>
__global__ __launch_bounds__(256) void gemm_kernel(
    float* __restrict__ dio, const float* __restrict__ Kt,
    const float* __restrict__ h, const float* __restrict__ wsum_arr,
    const float* __restrict__ bias, int N) {
    __shared__ float xs[32][256];   // 32 node rows
    __shared__ float wsl[16][256];  // K-chunk of transposed weights
    int tid = threadIdx.x;
    int m0 = blockIdx.x * 32;
    // stage x tile (each wave writes full contiguous rows -> conflict-free)
#pragma unroll
    for (int it = 0; it < 8; ++it) {
        int flat = it * 1024 + tid * 4;
        int m = flat >> 8, k = flat & 255;
        int n = m0 + m;
        float4 v = make_float4(0.f, 0.f, 0.f, 0.f);
        if (n < N) v = *(const float4*)(dio + (size_t)n * 256 + k);
        *(float4*)&xs[m][k] = v;
    }
    float acc[8][4];
#pragma unroll
    for (int r = 0; r < 8; ++r)
#pragma unroll
        for (int c = 0; c < 4; ++c) acc[r][c] = 0.f;

    int tj = tid & 63, tm = tid >> 6;   // thread owns cols tj*4..+3, rows tm*8..+7
    for (int kc = 0; kc < 256; kc += 16) {
        __syncthreads();
#pragma unroll
        for (int it = 0; it < 4; ++it) {
            int flat = it * 1024 + tid * 4;
            int kk = flat >> 8, j = flat & 255;
            *(float4*)&wsl[kk][j] = *(const float4*)(Kt + (size_t)(kc + kk) * 256 + j);
        }
        __syncthreads();
#pragma unroll
        for (int kk = 0; kk < 16; kk += 4) {
            float4 w0 = *(const float4*)&wsl[kk + 0][tj * 4];
            float4 w1 = *(const float4*)&wsl[kk + 1][tj * 4];
            float4 w2 = *(const float4*)&wsl[kk + 2][tj * 4];
            float4 w3 = *(const float4*)&wsl[kk + 3][tj * 4];
#pragma unroll
            for (int r = 0; r < 8; ++r) {
                float4 xv = *(const float4*)&xs[tm * 8 + r][kc + kk];
                acc[r][0] += xv.x * w0.x; acc[r][1] += xv.x * w0.y;
                acc[r][2] += xv.x * w0.z; acc[r][3] += xv.x * w0.w;
                acc[r][0] += xv.y * w1.x; acc[r][1] += xv.y * w1.y;
                acc[r][2] += xv.y * w1.z; acc[r][3] += xv.y * w1.w;
                acc[r][0] += xv.z * w2.x; acc[r][1] += xv.z * w2.y;
                acc[r][2] += xv.z * w2.z; acc[r][3] += xv.z * w2.w;
                acc[r][0] += xv.w * w3.x; acc[r][1] += xv.w * w3.y;
                acc[r][2] += xv.w * w3.z; acc[r][3] += xv.w * w3.w;
            }
        }
    }
    int j0 = tj * 4;
    float4 bv = *(const float4*)(bias + j0);
#pragma unroll
    for (int r = 0; r < 8; ++r) {
        int n = m0 + tm * 8 + r;
        if (n >= N) continue;
        if (PHASE == 1) {
            float ws = wsum_arr[n];
            float4 hv = *(const float4*)(h + (size_t)n * 256 + j0);
            float4 o;
            o.x = acc[r][0] + hv.x + bv.x * ws;
            o.y = acc[r][1] + hv.y + bv.y * ws;
            o.z = acc[r][2] + hv.z + bv.z * ws;
            o.w = acc[r][3] + hv.w + bv.w * ws;
            *(float4*)(dio + (size_t)n * 256 + j0) = o;
        } else {
            // permuted store: blade-major j -> channel-major (j&63)*4 + (j>>6)
            size_t base = (size_t)n * 256 + (size_t)(j0 & 63) * 4 + (j0 >> 6);
            dio[base + 0]  = acc[r][0] + bv.x;
            dio[base + 4]  = acc[r][1] + bv.y;
            dio[base + 8]  = acc[r][2] + bv.z;
            dio[base + 12] = acc[r][3] + bv.w;
        }
    }
}

static inline size_t align4(size_t x) { return (x + 3) & ~(size_t)3; }

extern "C" void kernel_launch(void* const* d_in, const int* in_sizes, int n_in,
                              void* d_out, int out_size, void* d_ws, size_t ws_size,
                              hipStream_t stream) {
    const float* h       = (const float*)d_in[0];
    const int*   ei      = (const int*)d_in[1];   // (2,E) row-major
    const int*   et      = (const int*)d_in[2];
    const float* rel_emb = (const float*)d_in[3];
    const float* msg_w   = (const float*)d_in[4];
    const float* msg_b   = (const float*)d_in[5];
    const float* upd_w   = (const float*)d_in[6];
    const float* upd_b   = (const float*)d_in[7];
    const float* gate_w  = (const float*)d_in[8];
    const float* gate_b  = (const float*)d_in[9];

    const int N = in_sizes[0] / 256;
    const int E = in_sizes[2];
    const int R = in_sizes[3] / 256;

    // workspace layout (u32/float units)
    u32* ws = (u32*)d_ws;
    size_t o = 0;
    u32* deg_src  = ws + o; o += align4((size_t)N);
    u32* deg_dst  = ws + o; o += align4((size_t)N);
    u32* offs     = ws + o; o += align4((size_t)N);
    u32* cursor   = ws + o; o += align4((size_t)N);
    u32* edge_ids = ws + o; o += align4((size_t)E);
    float* wsum   = (float*)(ws + o); o += align4((size_t)N);
    float* gate   = (float*)(ws + o); o += align4((size_t)R);
    float* Ktm    = (float*)(ws + o); o += 65536;
    float* Ktu    = (float*)(ws + o); o += 65536;
    if (ws_size < o * 4) return;  // insufficient scratch -> fail loudly

    float* out = (float*)d_out;

    // zero degree counters (deg_src & deg_dst are adjacent)
    hipMemsetAsync(deg_src, 0, (size_t)2 * align4((size_t)N) * 4, stream);

    build_mats_kernel<<<256, 256, 0, stream>>>(msg_w, upd_w, Ktm, Ktu);
    gate_kernel<<<(R + 3) / 4, 256, 0, stream>>>(rel_emb, gate_w, gate_b, gate, R);
    degree_kernel<<<(E + 255) / 256, 256, 0, stream>>>(ei, E, deg_src, deg_dst);
    scan_kernel<<<1, 1024, 0, stream>>>(deg_dst, offs, cursor, N);
    fill_kernel<<<(E + 255) / 256, 256, 0, stream>>>(ei, E, cursor, edge_ids);
    agg_kernel<<<(N + 3) / 4, 256, 0, stream>>>(h, rel_emb, ei, et, deg_src, deg_dst,
                                                offs, edge_ids, gate, out, wsum, E, N);
    gemm_kernel<1><<<(N + 31) / 32, 256, 0, stream>>>(out, Ktm, h, wsum, msg_b, N);
    gemm_kernel<2><<<(N + 31) / 32, 256, 0, stream>>>(out, Ktu, h, wsum, upd_b, N);
}

// Round 2
// 446.869 us; speedup vs baseline: 1.7901x; 1.7901x over previous
//
#include <hip/hip_runtime.h>
#include <math.h>

typedef unsigned int u32;
typedef __attribute__((ext_vector_type(8))) short bf16x8;   // 8 bf16 in 4 VGPRs
typedef __attribute__((ext_vector_type(4))) float f32x4;

__device__ inline unsigned short f2bf(float x) {  // round-to-nearest-even
    union { float f; u32 u; } v; v.f = x;
    u32 r = v.u + 0x7FFFu + ((v.u >> 16) & 1u);
    return (unsigned short)(r >> 16);
}

// ---------------------------------------------------------------------------
// Clifford GNN message passing, restructured:
//   h_agg = ML( sum_e w_e*(h[src] .* r[rel]) ) + msg_b * sum_e w_e
//   out   = UL( h + h_agg ) + upd_b   (channel-major permuted store)
// GEMMs run on bf16 MFMA (16x16x32), weights prebuilt as K[j][k] bf16.
// ---------------------------------------------------------------------------

// Build Clifford kernel matrices Kb[j][k] = K[j][k] in bf16 (k contiguous).
__global__ void build_mats_kernel(const float* __restrict__ msg_w,
                                  const float* __restrict__ upd_w,
                                  unsigned short* __restrict__ Kbm,
                                  unsigned short* __restrict__ Kbu) {
    const int   s_tab[16] = {0,1,2,3, 1,0,3,2, 2,3,0,1, 3,2,1,0};
    const float g_tab[16] = {1.f,1.f,1.f,-1.f, 1.f,1.f,-1.f,1.f,
                             1.f,1.f,1.f,-1.f, 1.f,1.f,1.f,1.f};
    int idx = blockIdx.x * 256 + threadIdx.x;   // idx = j*256 + i
    int j = idx >> 8, i = idx & 255;
    int ob = j >> 6, oc = j & 63, ib = i >> 6, ic = i & 63;
    int t = ob * 4 + ib;
    int widx = s_tab[t] * 4096 + oc * 64 + ic;  // w[s][oc][ic]
    float sg = g_tab[t];
    Kbm[idx] = f2bf(sg * msg_w[widx]);
    Kbu[idx] = f2bf(sg * upd_w[widx]);
}

// gate[r] = sigmoid( sum_j rel_emb[r, j] * gate_w[(j&63)*4 + (j>>6)] + gate_b )
__global__ void gate_kernel(const float* __restrict__ rel_emb,
                            const float* __restrict__ gate_w,
                            const float* __restrict__ gate_b,
                            float* __restrict__ gate, int R) {
    int wv = threadIdx.x >> 6, lane = threadIdx.x & 63;
    int r = blockIdx.x * 4 + wv;
    if (r >= R) return;
    float4 rv = *(const float4*)(rel_emb + (size_t)r * 256 + lane * 4);
    float s = 0.f;
    float rvv[4] = {rv.x, rv.y, rv.z, rv.w};
#pragma unroll
    for (int c = 0; c < 4; ++c) {
        int j = lane * 4 + c;
        s += rvv[c] * gate_w[(j & 63) * 4 + (j >> 6)];
    }
#pragma unroll
    for (int d = 32; d > 0; d >>= 1) s += __shfl_down(s, d);
    if (lane == 0) gate[r] = 1.0f / (1.0f + expf(-(s + gate_b[0])));
}

__global__ void degree_kernel(const int* __restrict__ ei, int E,
                              u32* __restrict__ deg_src, u32* __restrict__ deg_dst) {
    int e = blockIdx.x * 256 + threadIdx.x;
    if (e >= E) return;
    atomicAdd(&deg_src[ei[e]], 1u);
    atomicAdd(&deg_dst[ei[E + e]], 1u);
}

// Single-block exclusive scan of deg_dst -> offs and cursor (copy).
__global__ void scan_kernel(const u32* __restrict__ deg, u32* __restrict__ offs,
                            u32* __restrict__ cursor, int N) {
    __shared__ u32 wtot[16];
    __shared__ u32 wpre[17];
    __shared__ u32 running;
    int t = threadIdx.x, lane = t & 63, wv = t >> 6;
    if (t == 0) running = 0u;
    __syncthreads();
    for (int base = 0; base < N; base += 4096) {
        int i0 = base + t * 4;
        u32 v[4]; u32 s = 0;
#pragma unroll
        for (int c = 0; c < 4; ++c) { v[c] = (i0 + c < N) ? deg[i0 + c] : 0u; s += v[c]; }
        u32 sc = s;
#pragma unroll
        for (int d = 1; d < 64; d <<= 1) { u32 o = __shfl_up(sc, d); if (lane >= d) sc += o; }
        if (lane == 63) wtot[wv] = sc;
        __syncthreads();
        if (t < 16) {
            u32 x = wtot[t], xs2 = x;
#pragma unroll
            for (int d = 1; d < 16; d <<= 1) { u32 o = __shfl_up(xs2, d); if (t >= d) xs2 += o; }
            wpre[t] = xs2 - x;
            if (t == 15) wpre[16] = xs2;   // chunk total
        }
        __syncthreads();
        u32 excl = running + wpre[wv] + (sc - s);
#pragma unroll
        for (int c = 0; c < 4; ++c) {
            if (i0 + c < N) { offs[i0 + c] = excl; cursor[i0 + c] = excl; }
            excl += v[c];
        }
        __syncthreads();
        if (t == 0) running += wpre[16];
        __syncthreads();
    }
}

__global__ void fill_kernel(const int* __restrict__ ei, int E,
                            u32* __restrict__ cursor, u32* __restrict__ edge_ids) {
    int e = blockIdx.x * 256 + threadIdx.x;
    if (e >= E) return;
    int dst = ei[E + e];
    u32 pos = atomicAdd(&cursor[dst], 1u);
    edge_ids[pos] = (u32)e;
}

// One wave per node: agg[n] = sum_{e in bucket} w_e * h[src] .* r[rel];
// writes agg row into d_out and w-sum into wsum_arr.
__global__ void agg_kernel(const float* __restrict__ h,
                           const float* __restrict__ rel_emb,
                           const int* __restrict__ ei, const int* __restrict__ et,
                           const u32* __restrict__ deg_src,
                           const u32* __restrict__ deg_dst,
                           const u32* __restrict__ offs,
                           const u32* __restrict__ edge_ids,
                           const float* __restrict__ gate,
                           float* __restrict__ out, float* __restrict__ wsum_arr,
                           int E, int N) {
    int wv = threadIdx.x >> 6, lane = threadIdx.x & 63;
    int n = blockIdx.x * 4 + wv;
    if (n >= N) return;
    u32 dd = deg_dst[n];
    u32 off = offs[n];
    float ddf = (float)dd;
    float4 acc = make_float4(0.f, 0.f, 0.f, 0.f);
    float wsum = 0.f;
    for (u32 i = 0; i < dd; ++i) {
        u32 eid = edge_ids[off + i];
        int src = ei[eid];
        int rel = et[eid];
        float ds = (float)deg_src[src];
        float w = gate[rel] / sqrtf(fmaxf(ds * ddf, 1.0f));
        float4 hv = *(const float4*)(h + (size_t)src * 256 + lane * 4);
        float4 rv = *(const float4*)(rel_emb + (size_t)rel * 256 + lane * 4);
        acc.x += w * hv.x * rv.x;
        acc.y += w * hv.y * rv.y;
        acc.z += w * hv.z * rv.z;
        acc.w += w * hv.w * rv.w;
        wsum += w;
    }
    *(float4*)(out + (size_t)n * 256 + lane * 4) = acc;
    if (lane == 0) wsum_arr[n] = wsum;
}

// Fused double GEMM on MFMA. Per block: 32 rows.
//   t = agg @ Km^T + h + msg_b*wsum   (Km as Kbm[j][k] bf16)
//   y = t @ Ku^T + upd_b              -> permuted store out[n, (j&63)*4 + j>>6]
// xs LDS tile is XOR-swizzled: element (m,k) at ushort index m*256 + (k ^ ((m&7)<<3)).
__global__ __launch_bounds__(256) void fused_gemm_kernel(
    float* __restrict__ dio,
    const unsigned short* __restrict__ Kbm,
    const unsigned short* __restrict__ Kbu,
    const float* __restrict__ h,
    const float* __restrict__ wsum_arr,
    const float* __restrict__ msg_b,
    const float* __restrict__ upd_b,
    int N) {
    __shared__ __align__(16) unsigned short xs[32 * 256];  // 16 KiB bf16
    const int tid = threadIdx.x;
    const int lane = tid & 63;
    const int wv = tid >> 6;        // wave owns cols [wv*64, wv*64+64)
    const int l15 = lane & 15;
    const int kg = lane >> 4;       // k-group 0..3
    const int m0 = blockIdx.x * 32;
    const int jbase = wv * 64;

    // ---- stage agg (fp32 rows in dio) -> bf16 swizzled LDS ----
#pragma unroll
    for (int p = 0; p < 4; ++p) {
        int f = p * 2048 + tid * 8;
        int m = f >> 8;             // 0..31
        int k = f & 255;            // multiple of 8
        const float* src = dio + (size_t)(m0 + m) * 256 + k;
        float4 v0 = *(const float4*)(src);
        float4 v1 = *(const float4*)(src + 4);
        unsigned short tmp[8] = {f2bf(v0.x), f2bf(v0.y), f2bf(v0.z), f2bf(v0.w),
                                 f2bf(v1.x), f2bf(v1.y), f2bf(v1.z), f2bf(v1.w)};
        *(uint4*)&xs[m * 256 + (k ^ ((m & 7) << 3))] = *(const uint4*)tmp;
    }
    __syncthreads();

    f32x4 acc[2][4];

    // ================= phase A: acc = agg @ Km^T =================
#pragma unroll
    for (int mf = 0; mf < 2; ++mf)
#pragma unroll
        for (int nf = 0; nf < 4; ++nf) acc[mf][nf] = (f32x4)(0.f);

#pragma unroll
    for (int k0 = 0; k0 < 256; k0 += 32) {
        int kk = k0 + kg * 8;
        int ma = l15, mb = 16 + l15;
        bf16x8 a0 = *(const bf16x8*)&xs[ma * 256 + (kk ^ ((ma & 7) << 3))];
        bf16x8 a1 = *(const bf16x8*)&xs[mb * 256 + (kk ^ ((mb & 7) << 3))];
#pragma unroll
        for (int nf = 0; nf < 4; ++nf) {
            int j = jbase + nf * 16 + l15;
            bf16x8 b = *(const bf16x8*)(Kbm + (size_t)j * 256 + kk);
            acc[0][nf] = __builtin_amdgcn_mfma_f32_16x16x32_bf16(a0, b, acc[0][nf], 0, 0, 0);
            acc[1][nf] = __builtin_amdgcn_mfma_f32_16x16x32_bf16(a1, b, acc[1][nf], 0, 0, 0);
        }
    }
    __syncthreads();   // all phase-A reads of xs done before overwrite

    // ---- epilogue A: t = acc + h + msg_b*wsum ; t -> bf16 swizzled LDS ----
    float bjA[4];
#pragma unroll
    for (int nf = 0; nf < 4; ++nf) bjA[nf] = msg_b[jbase + nf * 16 + l15];
#pragma unroll
    for (int mf = 0; mf < 2; ++mf) {
#pragma unroll
        for (int r = 0; r < 4; ++r) {
            int m = mf * 16 + kg * 4 + r;             // D-frag row
            int row = m0 + m;
            float ws = wsum_arr[row];
            const float* hrow = h + (size_t)row * 256;
#pragma unroll
            for (int nf = 0; nf < 4; ++nf) {
                int j = jbase + nf * 16 + l15;        // D-frag col
                float t = acc[mf][nf][r] + hrow[j] + bjA[nf] * ws;
                xs[m * 256 + (j ^ ((m & 7) << 3))] = f2bf(t);
            }
        }
    }
    __syncthreads();

    // ================= phase B: acc = t @ Ku^T =================
#pragma unroll
    for (int mf = 0; mf < 2; ++mf)
#pragma unroll
        for (int nf = 0; nf < 4; ++nf) acc[mf][nf] = (f32x4)(0.f);

#pragma unroll
    for (int k0 = 0; k0 < 256; k0 += 32) {
        int kk = k0 + kg * 8;
        int ma = l15, mb = 16 + l15;
        bf16x8 a0 = *(const bf16x8*)&xs[ma * 256 + (kk ^ ((ma & 7) << 3))];
        bf16x8 a1 = *(const bf16x8*)&xs[mb * 256 + (kk ^ ((mb & 7) << 3))];
#pragma unroll
        for (int nf = 0; nf < 4; ++nf) {
            int j = jbase + nf * 16 + l15;
            bf16x8 b = *(const bf16x8*)(Kbu + (size_t)j * 256 + kk);
            acc[0][nf] = __builtin_amdgcn_mfma_f32_16x16x32_bf16(a0, b, acc[0][nf], 0, 0, 0);
            acc[1][nf] = __builtin_amdgcn_mfma_f32_16x16x32_bf16(a1, b, acc[1][nf], 0, 0, 0);
        }
    }

    // ---- epilogue B: y = acc + upd_b[j]; permuted (channel-major) store ----
#pragma unroll
    for (int nf = 0; nf < 4; ++nf) {
        int j = jbase + nf * 16 + l15;
        float bj = upd_b[j];
        int colout = (j & 63) * 4 + wv;               // j>>6 == wv for this wave
#pragma unroll
        for (int mf = 0; mf < 2; ++mf) {
#pragma unroll
            for (int r = 0; r < 4; ++r) {
                int row = m0 + mf * 16 + kg * 4 + r;
                if (row < N) dio[(size_t)row * 256 + colout] = acc[mf][nf][r] + bj;
            }
        }
    }
}

static inline size_t align4(size_t x) { return (x + 3) & ~(size_t)3; }

extern "C" void kernel_launch(void* const* d_in, const int* in_sizes, int n_in,
                              void* d_out, int out_size, void* d_ws, size_t ws_size,
                              hipStream_t stream) {
    const float* h       = (const float*)d_in[0];
    const int*   ei      = (const int*)d_in[1];   // (2,E) row-major
    const int*   et      = (const int*)d_in[2];
    const float* rel_emb = (const float*)d_in[3];
    const float* msg_w   = (const float*)d_in[4];
    const float* msg_b   = (const float*)d_in[5];
    const float* upd_w   = (const float*)d_in[6];
    const float* upd_b   = (const float*)d_in[7];
    const float* gate_w  = (const float*)d_in[8];
    const float* gate_b  = (const float*)d_in[9];

    const int N = in_sizes[0] / 256;
    const int E = in_sizes[2];
    const int R = in_sizes[3] / 256;

    // workspace layout (u32 units)
    u32* ws = (u32*)d_ws;
    size_t o = 0;
    u32* deg_src  = ws + o; o += align4((size_t)N);
    u32* deg_dst  = ws + o; o += align4((size_t)N);
    u32* offs     = ws + o; o += align4((size_t)N);
    u32* cursor   = ws + o; o += align4((size_t)N);
    u32* edge_ids = ws + o; o += align4((size_t)E);
    float* wsum   = (float*)(ws + o); o += align4((size_t)N);
    float* gate   = (float*)(ws + o); o += align4((size_t)R);
    unsigned short* Kbm = (unsigned short*)(ws + o); o += 32768;  // 256*256 bf16
    unsigned short* Kbu = (unsigned short*)(ws + o); o += 32768;
    if (ws_size < o * 4) return;  // insufficient scratch -> fail loudly

    float* out = (float*)d_out;

    // zero degree counters (deg_src & deg_dst are adjacent)
    hipMemsetAsync(deg_src, 0, (size_t)2 * align4((size_t)N) * 4, stream);

    build_mats_kernel<<<256, 256, 0, stream>>>(msg_w, upd_w, Kbm, Kbu);
    gate_kernel<<<(R + 3) / 4, 256, 0, stream>>>(rel_emb, gate_w, gate_b, gate, R);
    degree_kernel<<<(E + 255) / 256, 256, 0, stream>>>(ei, E, deg_src, deg_dst);
    scan_kernel<<<1, 1024, 0, stream>>>(deg_dst, offs, cursor, N);
    fill_kernel<<<(E + 255) / 256, 256, 0, stream>>>(ei, E, cursor, edge_ids);
    agg_kernel<<<(N + 3) / 4, 256, 0, stream>>>(h, rel_emb, ei, et, deg_src, deg_dst,
                                                offs, edge_ids, gate, out, wsum, E, N);
    fused_gemm_kernel<<<(N + 31) / 32, 256, 0, stream>>>(out, Kbm, Kbu, h, wsum,
                                                         msg_b, upd_b, N);
}